// Round 1
// baseline (450.473 us; speedup 1.0000x reference)
//
#include <hip/hip_runtime.h>
#include <hip/hip_bf16.h>

#define NEG_SLOPE 0.2f

// ---------------- CSR build ----------------

__global__ void count_kernel(const int* __restrict__ ei, int e, int n, int* __restrict__ cnt) {
    int i = blockIdx.x * blockDim.x + threadIdx.x;
    int total = e + n;
    if (i >= total) return;
    int dst = (i < e) ? ei[e + i] : (i - e);
    atomicAdd(&cnt[dst], 1);
}

__global__ __launch_bounds__(1024) void scan_kernel(const int* __restrict__ cnt, int* __restrict__ rowptr, int n) {
    __shared__ int ssum[1024];
    int tid = threadIdx.x;
    int chunk = (n + 1023) / 1024;
    int beg = tid * chunk;
    int end = min(beg + chunk, n);
    int s = 0;
    for (int i = beg; i < end; ++i) s += cnt[i];
    ssum[tid] = s;
    __syncthreads();
    // inclusive scan (Hillis-Steele)
    for (int off = 1; off < 1024; off <<= 1) {
        int v = (tid >= off) ? ssum[tid - off] : 0;
        __syncthreads();
        ssum[tid] += v;
        __syncthreads();
    }
    int run = (tid > 0) ? ssum[tid - 1] : 0;  // exclusive base
    for (int i = beg; i < end; ++i) {
        rowptr[i] = run;
        run += cnt[i];
    }
    if (tid == 1023) rowptr[n] = ssum[1023];
}

__global__ void fill_kernel(const int* __restrict__ ei, int e, int n,
                            const int* __restrict__ rowptr, int* __restrict__ fillc,
                            int* __restrict__ colsrc) {
    int i = blockIdx.x * blockDim.x + threadIdx.x;
    int total = e + n;
    if (i >= total) return;
    int src, dst;
    if (i < e) { src = ei[i]; dst = ei[e + i]; }
    else       { src = i - e; dst = i - e; }
    int pos = atomicAdd(&fillc[dst], 1);
    colsrc[rowptr[dst] + pos] = src;
}

// ---------------- GEMM: O[n,128] = X[n,128] @ W[128,128] ----------------

__global__ __launch_bounds__(256) void gemm_kernel(const float* __restrict__ X,
                                                   const float* __restrict__ W,
                                                   float* __restrict__ O, int n) {
    __shared__ float sW[128][129];    // [k][c], padded
    __shared__ float sXt[128][65];    // [k][r], padded
    int tid = threadIdx.x;
    int row0 = blockIdx.x * 64;

    // load W (128x128) into LDS
    for (int i = tid; i < 128 * 32; i += 256) {
        float4 v = ((const float4*)W)[i];
        int flat = i * 4;
        int r = flat >> 7, c = flat & 127;
        sW[r][c] = v.x; sW[r][c + 1] = v.y; sW[r][c + 2] = v.z; sW[r][c + 3] = v.w;
    }
    // load X tile (64x128) transposed into LDS
    for (int i = tid; i < 64 * 32; i += 256) {
        int flat = i * 4;
        int r = flat >> 7, c = flat & 127;
        int gr = row0 + r;
        float4 v = make_float4(0.f, 0.f, 0.f, 0.f);
        if (gr < n) v = ((const float4*)(X + (size_t)gr * 128))[c >> 2];
        sXt[c][r] = v.x; sXt[c + 1][r] = v.y; sXt[c + 2][r] = v.z; sXt[c + 3][r] = v.w;
    }
    __syncthreads();

    int tx = tid & 15;   // col group (8 cols)
    int ty = tid >> 4;   // row group (4 rows)
    float acc[4][8];
#pragma unroll
    for (int i = 0; i < 4; ++i)
#pragma unroll
        for (int j = 0; j < 8; ++j) acc[i][j] = 0.f;

#pragma unroll 4
    for (int k = 0; k < 128; ++k) {
        float xv[4], wv[8];
#pragma unroll
        for (int i = 0; i < 4; ++i) xv[i] = sXt[k][ty * 4 + i];
#pragma unroll
        for (int j = 0; j < 8; ++j) wv[j] = sW[k][tx * 8 + j];
#pragma unroll
        for (int i = 0; i < 4; ++i)
#pragma unroll
            for (int j = 0; j < 8; ++j) acc[i][j] += xv[i] * wv[j];
    }

#pragma unroll
    for (int i = 0; i < 4; ++i) {
        int gr = row0 + ty * 4 + i;
        if (gr < n) {
            float4 a = make_float4(acc[i][0], acc[i][1], acc[i][2], acc[i][3]);
            float4 b = make_float4(acc[i][4], acc[i][5], acc[i][6], acc[i][7]);
            float4* p = (float4*)(O + (size_t)gr * 128 + tx * 8);
            p[0] = a; p[1] = b;
        }
    }
}

// ---------------- per-node alpha_src / alpha_dst ----------------

template <int H, int C>
__global__ __launch_bounds__(256) void alpha_kernel(const float* __restrict__ hbuf,
                                                    const float* __restrict__ asrc,
                                                    const float* __restrict__ adst,
                                                    float* __restrict__ as_out,
                                                    float* __restrict__ ad_out, int n) {
    int node = blockIdx.x * 4 + (threadIdx.x >> 6);
    int lane = threadIdx.x & 63;
    if (node >= n) return;
    float2 hv = ((const float2*)(hbuf + (size_t)node * 128))[lane];
    float2 sv = ((const float2*)asrc)[lane];
    float2 dv = ((const float2*)adst)[lane];
    float ps = hv.x * sv.x + hv.y * sv.y;
    float pd = hv.x * dv.x + hv.y * dv.y;
    constexpr int LPH = C / 2;  // lanes per head
#pragma unroll
    for (int off = 1; off < LPH; off <<= 1) {
        ps += __shfl_xor(ps, off, 64);
        pd += __shfl_xor(pd, off, 64);
    }
    if ((lane & (LPH - 1)) == 0) {
        int h = lane / LPH;
        as_out[(size_t)node * H + h] = ps;
        ad_out[(size_t)node * H + h] = pd;
    }
}

// ---------------- per-node aggregation (segment softmax + weighted sum) ----------------

template <int H, int C>
__global__ __launch_bounds__(256) void agg_kernel(const int* __restrict__ rowptr,
                                                  const int* __restrict__ colsrc,
                                                  const float* __restrict__ hbuf,
                                                  const float* __restrict__ as,
                                                  const float* __restrict__ ad,
                                                  const float* __restrict__ bias,
                                                  float* __restrict__ out, int n, int applyElu) {
    int node = blockIdx.x * 4 + (threadIdx.x >> 6);
    int lane = threadIdx.x & 63;
    if (node >= n) return;
    int beg = rowptr[node];
    int end = rowptr[node + 1];

    float adv[H];
#pragma unroll
    for (int h = 0; h < H; ++h) adv[h] = ad[(size_t)node * H + h];

    // phase 1: per-head max over incoming edges
    float m[H];
#pragma unroll
    for (int h = 0; h < H; ++h) m[h] = -1e30f;
    for (int i = beg + lane; i < end; i += 64) {
        int s = colsrc[i];
#pragma unroll
        for (int h = 0; h < H; ++h) {
            float ev = as[(size_t)s * H + h] + adv[h];
            ev = (ev > 0.f) ? ev : NEG_SLOPE * ev;
            m[h] = fmaxf(m[h], ev);
        }
    }
#pragma unroll
    for (int h = 0; h < H; ++h)
#pragma unroll
        for (int off = 32; off > 0; off >>= 1) m[h] = fmaxf(m[h], __shfl_xor(m[h], off, 64));

    // phase 2: denom
    float d[H];
#pragma unroll
    for (int h = 0; h < H; ++h) d[h] = 0.f;
    for (int i = beg + lane; i < end; i += 64) {
        int s = colsrc[i];
#pragma unroll
        for (int h = 0; h < H; ++h) {
            float ev = as[(size_t)s * H + h] + adv[h];
            ev = (ev > 0.f) ? ev : NEG_SLOPE * ev;
            d[h] += __expf(ev - m[h]);
        }
    }
#pragma unroll
    for (int h = 0; h < H; ++h)
#pragma unroll
        for (int off = 32; off > 0; off >>= 1) d[h] += __shfl_xor(d[h], off, 64);

    // phase 3: weighted accumulation; lane owns channels 2*lane, 2*lane+1
    constexpr int LPH = C / 2;
    int headc = lane / LPH;
    float mh = m[headc], dh = d[headc], adh = adv[headc];
    float acc0 = 0.f, acc1 = 0.f;
#pragma unroll 2
    for (int i = beg; i < end; ++i) {
        int s = colsrc[i];
        float ev = as[(size_t)s * H + headc] + adh;
        ev = (ev > 0.f) ? ev : NEG_SLOPE * ev;
        float alpha = __expf(ev - mh) / dh;
        float2 hv = ((const float2*)(hbuf + (size_t)s * 128))[lane];
        acc0 += alpha * hv.x;
        acc1 += alpha * hv.y;
    }
    int c0 = 2 * lane;
    float r0 = acc0 + bias[c0];
    float r1 = acc1 + bias[c0 + 1];
    if (applyElu) {
        r0 = (r0 > 0.f) ? r0 : expm1f(r0);
        r1 = (r1 > 0.f) ? r1 : expm1f(r1);
    }
    ((float2*)(out + (size_t)node * 128))[lane] = make_float2(r0, r1);
}

// ---------------- launch ----------------

extern "C" void kernel_launch(void* const* d_in, const int* in_sizes, int n_in,
                              void* d_out, int out_size, void* d_ws, size_t ws_size,
                              hipStream_t stream) {
    const float* x    = (const float*)d_in[0];
    const int*   ei   = (const int*)d_in[1];
    const float* W1   = (const float*)d_in[2];
    const float* a_s1 = (const float*)d_in[3];
    const float* a_d1 = (const float*)d_in[4];
    const float* b1   = (const float*)d_in[5];
    const float* W2   = (const float*)d_in[6];
    const float* a_s2 = (const float*)d_in[7];
    const float* a_d2 = (const float*)d_in[8];
    const float* b2   = (const float*)d_in[9];

    const int n  = in_sizes[0] / 128;
    const int e  = in_sizes[1] / 2;
    const int en = e + n;

    char* ws = (char*)d_ws;
    size_t off = 0;
    auto alloc = [&](size_t bytes) -> void* {
        void* p = ws + off;
        off += (bytes + 255) & ~(size_t)255;
        return p;
    };
    float* h1     = (float*)alloc((size_t)n * 128 * 4);  // layer-1 features; reused for layer-2 features
    float* hmid   = (float*)alloc((size_t)n * 128 * 4);  // ELU output of layer 1
    float* as1    = (float*)alloc((size_t)n * 8 * 4);
    float* ad1    = (float*)alloc((size_t)n * 8 * 4);
    float* as2    = (float*)alloc((size_t)n * 4);
    float* ad2    = (float*)alloc((size_t)n * 4);
    int*   cnt    = (int*)alloc((size_t)n * 4 * 2);      // cnt + fillc adjacent (single memset)
    int*   fillc  = cnt + n;
    int*   rowptr = (int*)alloc((size_t)(n + 1) * 4);
    int*   colsrc = (int*)alloc((size_t)en * 4);

    // CSR build (same graph for both layers)
    hipMemsetAsync(cnt, 0, (size_t)n * 8, stream);
    count_kernel<<<(en + 255) / 256, 256, 0, stream>>>(ei, e, n, cnt);
    scan_kernel<<<1, 1024, 0, stream>>>(cnt, rowptr, n);
    fill_kernel<<<(en + 255) / 256, 256, 0, stream>>>(ei, e, n, rowptr, fillc, colsrc);

    int gemm_grid = (n + 63) / 64;
    int node_grid = (n + 3) / 4;

    // layer 1
    gemm_kernel<<<gemm_grid, 256, 0, stream>>>(x, W1, h1, n);
    alpha_kernel<8, 16><<<node_grid, 256, 0, stream>>>(h1, a_s1, a_d1, as1, ad1, n);
    agg_kernel<8, 16><<<node_grid, 256, 0, stream>>>(rowptr, colsrc, h1, as1, ad1, b1, hmid, n, 1);

    // layer 2
    gemm_kernel<<<gemm_grid, 256, 0, stream>>>(hmid, W2, h1, n);
    alpha_kernel<1, 128><<<node_grid, 256, 0, stream>>>(h1, a_s2, a_d2, as2, ad2, n);
    agg_kernel<1, 128><<<node_grid, 256, 0, stream>>>(rowptr, colsrc, h1, as2, ad2, b2, (float*)d_out, n, 0);

    (void)n_in; (void)out_size; (void)ws_size;
}

// Round 2
// 348.330 us; speedup vs baseline: 1.2932x; 1.2932x over previous
//
#include <hip/hip_runtime.h>
#include <hip/hip_bf16.h>

#define NEG_SLOPE 0.2f

// ---------------- CSR build ----------------

__global__ void count_kernel(const int* __restrict__ ei, int e, int n, int* __restrict__ cnt) {
    int i = blockIdx.x * blockDim.x + threadIdx.x;
    int total = e + n;
    if (i >= total) return;
    int dst = (i < e) ? ei[e + i] : (i - e);
    atomicAdd(&cnt[dst], 1);
}

__global__ __launch_bounds__(1024) void scan_kernel(const int* __restrict__ cnt, int* __restrict__ rowptr, int n) {
    __shared__ int wsum[16];
    __shared__ int wbase[16];
    int tid = threadIdx.x;
    int wid = tid >> 6, lane = tid & 63;
    int per_wave = ((n + 1023) / 1024) * 64;
    int beg = wid * per_wave;
    int end = min(beg + per_wave, n);
    // pass 1: wave total (coalesced)
    int s = 0;
    for (int i = beg + lane; i < end; i += 64) s += cnt[i];
#pragma unroll
    for (int off = 32; off; off >>= 1) s += __shfl_xor(s, off, 64);
    if (lane == 0) wsum[wid] = s;
    __syncthreads();
    if (tid == 0) {
        int run = 0;
        for (int w = 0; w < 16; ++w) { wbase[w] = run; run += wsum[w]; }
        rowptr[n] = run;
    }
    __syncthreads();
    int base = wbase[wid];
    for (int i0 = beg; i0 < end; i0 += 64) {
        int i = i0 + lane;
        int v = (i < end) ? cnt[i] : 0;
        int incl = v;
#pragma unroll
        for (int off = 1; off < 64; off <<= 1) {
            int t = __shfl_up(incl, off, 64);
            if (lane >= off) incl += t;
        }
        if (i < end) rowptr[i] = base + incl - v;  // exclusive
        base += __shfl(incl, 63, 64);
    }
}

__global__ void fill_kernel(const int* __restrict__ ei, int e, int n,
                            const int* __restrict__ rowptr, int* __restrict__ fillc,
                            int* __restrict__ colsrc) {
    int i = blockIdx.x * blockDim.x + threadIdx.x;
    int total = e + n;
    if (i >= total) return;
    int src, dst;
    if (i < e) { src = ei[i]; dst = ei[e + i]; }
    else       { src = i - e; dst = i - e; }
    int pos = atomicAdd(&fillc[dst], 1);
    colsrc[rowptr[dst] + pos] = src;
}

// ---------------- GEMM + fused alpha: O = X@W, as/ad = per-head dots ----------------

template <int H>
__global__ __launch_bounds__(256) void gemm_alpha_kernel(const float* __restrict__ X,
                                                         const float* __restrict__ W,
                                                         const float* __restrict__ asrc,
                                                         const float* __restrict__ adst,
                                                         float* __restrict__ O,
                                                         float* __restrict__ as_out,
                                                         float* __restrict__ ad_out, int n) {
    __shared__ float sW[128][129];    // [k][c]
    __shared__ float sXt[128][65];    // [k][r]
    int tid = threadIdx.x;
    int row0 = blockIdx.x * 64;

    for (int i = tid; i < 128 * 32; i += 256) {
        float4 v = ((const float4*)W)[i];
        int flat = i * 4;
        int r = flat >> 7, c = flat & 127;
        sW[r][c] = v.x; sW[r][c + 1] = v.y; sW[r][c + 2] = v.z; sW[r][c + 3] = v.w;
    }
    for (int i = tid; i < 64 * 32; i += 256) {
        int flat = i * 4;
        int r = flat >> 7, c = flat & 127;
        int gr = row0 + r;
        float4 v = make_float4(0.f, 0.f, 0.f, 0.f);
        if (gr < n) v = ((const float4*)(X + (size_t)gr * 128))[c >> 2];
        sXt[c][r] = v.x; sXt[c + 1][r] = v.y; sXt[c + 2][r] = v.z; sXt[c + 3][r] = v.w;
    }
    __syncthreads();

    int tx = tid & 15;   // col group (8 cols)
    int ty = tid >> 4;   // row group (4 rows)
    float acc[4][8];
#pragma unroll
    for (int i = 0; i < 4; ++i)
#pragma unroll
        for (int j = 0; j < 8; ++j) acc[i][j] = 0.f;

#pragma unroll 4
    for (int k = 0; k < 128; ++k) {
        float xv[4], wv[8];
#pragma unroll
        for (int i = 0; i < 4; ++i) xv[i] = sXt[k][ty * 4 + i];
#pragma unroll
        for (int j = 0; j < 8; ++j) wv[j] = sW[k][tx * 8 + j];
#pragma unroll
        for (int i = 0; i < 4; ++i)
#pragma unroll
            for (int j = 0; j < 8; ++j) acc[i][j] += xv[i] * wv[j];
    }

    // attention vectors for this thread's 8 columns
    float av[8], dv[8];
#pragma unroll
    for (int j = 0; j < 8; ++j) {
        av[j] = asrc[tx * 8 + j];
        dv[j] = adst[tx * 8 + j];
    }
    constexpr int TXPH = (128 / H) / 8;  // tx groups per head: H=8 -> 2, H=1 -> 16

#pragma unroll
    for (int i = 0; i < 4; ++i) {
        int gr = row0 + ty * 4 + i;
        // write h row
        if (gr < n) {
            float4 a = make_float4(acc[i][0], acc[i][1], acc[i][2], acc[i][3]);
            float4 b = make_float4(acc[i][4], acc[i][5], acc[i][6], acc[i][7]);
            float4* p = (float4*)(O + (size_t)gr * 128 + tx * 8);
            p[0] = a; p[1] = b;
        }
        // fused alpha dots
        float ps = 0.f, pd = 0.f;
#pragma unroll
        for (int j = 0; j < 8; ++j) { ps += acc[i][j] * av[j]; pd += acc[i][j] * dv[j]; }
#pragma unroll
        for (int off = 1; off < TXPH; off <<= 1) {
            ps += __shfl_xor(ps, off, 64);
            pd += __shfl_xor(pd, off, 64);
        }
        if (gr < n && (tx & (TXPH - 1)) == 0) {
            int h = tx / TXPH;
            as_out[(size_t)gr * H + h] = ps;
            ad_out[(size_t)gr * H + h] = pd;
        }
    }
}

// ---------------- single-pass aggregation (max-free softmax) ----------------
// wave per node; lane = slot(0..3) x chgroup(0..15); 4 edges in flight, 8 ch/lane

template <int H>
__global__ __launch_bounds__(256) void agg_kernel(const int* __restrict__ rowptr,
                                                  const int* __restrict__ colsrc,
                                                  const float* __restrict__ hbuf,
                                                  const float* __restrict__ as,
                                                  const float* __restrict__ ad,
                                                  const float* __restrict__ bias,
                                                  float* __restrict__ out, int n, int applyElu) {
    int node = blockIdx.x * 4 + (threadIdx.x >> 6);
    int lane = threadIdx.x & 63;
    if (node >= n) return;
    int beg = rowptr[node];
    int end = rowptr[node + 1];

    int slot = lane >> 4;   // which edge in the group of 4
    int cl = lane & 15;     // channel group: channels cl*8 .. cl*8+7
    int head = (H == 8) ? (cl >> 1) : 0;
    float adh = ad[(size_t)node * H + head];

    float4 acc0 = make_float4(0.f, 0.f, 0.f, 0.f);
    float4 acc1 = make_float4(0.f, 0.f, 0.f, 0.f);
    float den = 0.f;

#pragma unroll 2
    for (int i = beg + slot; i < end; i += 4) {
        int s = colsrc[i];
        float ev = as[(size_t)s * H + head] + adh;
        ev = (ev > 0.f) ? ev : NEG_SLOPE * ev;
        float w = __expf(ev);
        den += w;
        const float4* hp = (const float4*)(hbuf + (size_t)s * 128 + cl * 8);
        float4 h0 = hp[0];
        float4 h1 = hp[1];
        acc0.x += w * h0.x; acc0.y += w * h0.y; acc0.z += w * h0.z; acc0.w += w * h0.w;
        acc1.x += w * h1.x; acc1.y += w * h1.y; acc1.z += w * h1.z; acc1.w += w * h1.w;
    }

    // reduce over the 4 slots (lane strides 16, 32)
#pragma unroll
    for (int off = 16; off <= 32; off <<= 1) {
        acc0.x += __shfl_xor(acc0.x, off, 64); acc0.y += __shfl_xor(acc0.y, off, 64);
        acc0.z += __shfl_xor(acc0.z, off, 64); acc0.w += __shfl_xor(acc0.w, off, 64);
        acc1.x += __shfl_xor(acc1.x, off, 64); acc1.y += __shfl_xor(acc1.y, off, 64);
        acc1.z += __shfl_xor(acc1.z, off, 64); acc1.w += __shfl_xor(acc1.w, off, 64);
        den += __shfl_xor(den, off, 64);
    }

    if (slot == 0) {
        float inv = 1.0f / den;
        float4 bb0 = ((const float4*)bias)[cl * 2];
        float4 bb1 = ((const float4*)bias)[cl * 2 + 1];
        float4 r0, r1;
        r0.x = acc0.x * inv + bb0.x; r0.y = acc0.y * inv + bb0.y;
        r0.z = acc0.z * inv + bb0.z; r0.w = acc0.w * inv + bb0.w;
        r1.x = acc1.x * inv + bb1.x; r1.y = acc1.y * inv + bb1.y;
        r1.z = acc1.z * inv + bb1.z; r1.w = acc1.w * inv + bb1.w;
        if (applyElu) {
            r0.x = (r0.x > 0.f) ? r0.x : expm1f(r0.x);
            r0.y = (r0.y > 0.f) ? r0.y : expm1f(r0.y);
            r0.z = (r0.z > 0.f) ? r0.z : expm1f(r0.z);
            r0.w = (r0.w > 0.f) ? r0.w : expm1f(r0.w);
            r1.x = (r1.x > 0.f) ? r1.x : expm1f(r1.x);
            r1.y = (r1.y > 0.f) ? r1.y : expm1f(r1.y);
            r1.z = (r1.z > 0.f) ? r1.z : expm1f(r1.z);
            r1.w = (r1.w > 0.f) ? r1.w : expm1f(r1.w);
        }
        float4* p = (float4*)(out + (size_t)node * 128 + cl * 8);
        p[0] = r0; p[1] = r1;
    }
}

// ---------------- launch ----------------

extern "C" void kernel_launch(void* const* d_in, const int* in_sizes, int n_in,
                              void* d_out, int out_size, void* d_ws, size_t ws_size,
                              hipStream_t stream) {
    const float* x    = (const float*)d_in[0];
    const int*   ei   = (const int*)d_in[1];
    const float* W1   = (const float*)d_in[2];
    const float* a_s1 = (const float*)d_in[3];
    const float* a_d1 = (const float*)d_in[4];
    const float* b1   = (const float*)d_in[5];
    const float* W2   = (const float*)d_in[6];
    const float* a_s2 = (const float*)d_in[7];
    const float* a_d2 = (const float*)d_in[8];
    const float* b2   = (const float*)d_in[9];

    const int n  = in_sizes[0] / 128;
    const int e  = in_sizes[1] / 2;
    const int en = e + n;

    char* ws = (char*)d_ws;
    size_t off = 0;
    auto alloc = [&](size_t bytes) -> void* {
        void* p = ws + off;
        off += (bytes + 255) & ~(size_t)255;
        return p;
    };
    float* h1     = (float*)alloc((size_t)n * 128 * 4);
    float* hmid   = (float*)alloc((size_t)n * 128 * 4);
    float* as1    = (float*)alloc((size_t)n * 8 * 4);
    float* ad1    = (float*)alloc((size_t)n * 8 * 4);
    float* as2    = (float*)alloc((size_t)n * 4);
    float* ad2    = (float*)alloc((size_t)n * 4);
    int*   cnt    = (int*)alloc((size_t)n * 4 * 2);
    int*   fillc  = cnt + n;
    int*   rowptr = (int*)alloc((size_t)(n + 1) * 4);
    int*   colsrc = (int*)alloc((size_t)en * 4);

    // CSR build (same graph both layers)
    hipMemsetAsync(cnt, 0, (size_t)n * 8, stream);
    count_kernel<<<(en + 255) / 256, 256, 0, stream>>>(ei, e, n, cnt);
    scan_kernel<<<1, 1024, 0, stream>>>(cnt, rowptr, n);
    fill_kernel<<<(en + 255) / 256, 256, 0, stream>>>(ei, e, n, rowptr, fillc, colsrc);

    int gemm_grid = (n + 63) / 64;
    int node_grid = (n + 3) / 4;

    // layer 1
    gemm_alpha_kernel<8><<<gemm_grid, 256, 0, stream>>>(x, W1, a_s1, a_d1, h1, as1, ad1, n);
    agg_kernel<8><<<node_grid, 256, 0, stream>>>(rowptr, colsrc, h1, as1, ad1, b1, hmid, n, 1);

    // layer 2
    gemm_alpha_kernel<1><<<gemm_grid, 256, 0, stream>>>(hmid, W2, a_s2, a_d2, h1, as2, ad2, n);
    agg_kernel<1><<<node_grid, 256, 0, stream>>>(rowptr, colsrc, h1, as2, ad2, b2, (float*)d_out, n, 0);

    (void)n_in; (void)out_size; (void)ws_size;
}

// Round 3
// 269.889 us; speedup vs baseline: 1.6691x; 1.2906x over previous
//
#include <hip/hip_runtime.h>
#include <hip/hip_bf16.h>

#define NEG_SLOPE 0.2f

// ---------------- CSR build ----------------

__global__ void count_kernel(const int* __restrict__ ei, int e, int n, int* __restrict__ cnt) {
    int i = blockIdx.x * blockDim.x + threadIdx.x;
    int total = e + n;
    if (i >= total) return;
    int dst = (i < e) ? ei[e + i] : (i - e);
    atomicAdd(&cnt[dst], 1);
}

__global__ __launch_bounds__(1024) void scan_kernel(const int* __restrict__ cnt, int* __restrict__ rowptr, int n) {
    __shared__ int wsum[16];
    __shared__ int wbase[16];
    int tid = threadIdx.x;
    int wid = tid >> 6, lane = tid & 63;
    int per_wave = ((n + 1023) / 1024) * 64;
    int beg = wid * per_wave;
    int end = min(beg + per_wave, n);
    int s = 0;
    for (int i = beg + lane; i < end; i += 64) s += cnt[i];
#pragma unroll
    for (int off = 32; off; off >>= 1) s += __shfl_xor(s, off, 64);
    if (lane == 0) wsum[wid] = s;
    __syncthreads();
    if (tid == 0) {
        int run = 0;
        for (int w = 0; w < 16; ++w) { wbase[w] = run; run += wsum[w]; }
        rowptr[n] = run;
    }
    __syncthreads();
    int base = wbase[wid];
    for (int i0 = beg; i0 < end; i0 += 64) {
        int i = i0 + lane;
        int v = (i < end) ? cnt[i] : 0;
        int incl = v;
#pragma unroll
        for (int off = 1; off < 64; off <<= 1) {
            int t = __shfl_up(incl, off, 64);
            if (lane >= off) incl += t;
        }
        if (i < end) rowptr[i] = base + incl - v;
        base += __shfl(incl, 63, 64);
    }
}

__global__ void fill_kernel(const int* __restrict__ ei, int e, int n,
                            const int* __restrict__ rowptr, int* __restrict__ fillc,
                            int* __restrict__ colsrc) {
    int i = blockIdx.x * blockDim.x + threadIdx.x;
    int total = e + n;
    if (i >= total) return;
    int src, dst;
    if (i < e) { src = ei[i]; dst = ei[e + i]; }
    else       { src = i - e; dst = i - e; }
    int pos = atomicAdd(&fillc[dst], 1);
    colsrc[rowptr[dst] + pos] = src;
}

// ---------------- GEMM + fused alpha ----------------
// BM=64 rows/block, BN=128 (full), BK=32 k-chunk, 256 threads.
// thread: tx=tid&15 (cols tx*4..+3 and 64+tx*4..+3), ty=tid>>4 (rows ty*4..+3)

template <int H>
__global__ __launch_bounds__(256) void gemm_alpha_kernel(const float* __restrict__ X,
                                                         const float* __restrict__ W,
                                                         const float* __restrict__ asrc,
                                                         const float* __restrict__ adst,
                                                         float* __restrict__ O,
                                                         float* __restrict__ as_out,
                                                         float* __restrict__ ad_out, int n) {
    __shared__ float sW[32][128];   // k-chunk of W, direct layout
    __shared__ float sX[64][36];    // row-major X chunk, padded (144B rows, 16B-aligned)
    int tid = threadIdx.x;
    int row0 = blockIdx.x * 64;
    int tx = tid & 15, ty = tid >> 4;
    int tx4 = tx * 4, ty4 = ty * 4;

    // load-index precompute
    int xr0 = tid >> 3;            // row for first X float4 (0..31)
    int xc0 = (tid & 7) * 4;       // col within chunk

    float4 xp[2];  // X prefetch regs
    float4 wp[4];  // W prefetch regs

    auto load_chunk = [&](int kc) {
        int k0 = kc * 32;
#pragma unroll
        for (int t = 0; t < 2; ++t) {
            int r = xr0 + t * 32;
            int gr = row0 + r;
            xp[t] = make_float4(0.f, 0.f, 0.f, 0.f);
            if (gr < n) xp[t] = *(const float4*)(X + (size_t)gr * 128 + k0 + xc0);
        }
#pragma unroll
        for (int t = 0; t < 4; ++t) {
            int f = tid + t * 256;       // 0..1023 over 32x32 float4 grid
            int kr = f >> 5, c4 = (f & 31) * 4;
            wp[t] = *(const float4*)(W + (size_t)(k0 + kr) * 128 + c4);
        }
    };

    float acc0[4][4], acc1[4][4];
#pragma unroll
    for (int i = 0; i < 4; ++i)
#pragma unroll
        for (int j = 0; j < 4; ++j) { acc0[i][j] = 0.f; acc1[i][j] = 0.f; }

    load_chunk(0);

    for (int kc = 0; kc < 4; ++kc) {
        __syncthreads();
        // store prefetched chunk to LDS
#pragma unroll
        for (int t = 0; t < 2; ++t) {
            int r = xr0 + t * 32;
            *(float4*)&sX[r][xc0] = xp[t];
        }
#pragma unroll
        for (int t = 0; t < 4; ++t) {
            int f = tid + t * 256;
            int kr = f >> 5, c4 = (f & 31) * 4;
            *(float4*)&sW[kr][c4] = wp[t];
        }
        __syncthreads();
        if (kc < 3) load_chunk(kc + 1);

#pragma unroll
        for (int k4 = 0; k4 < 32; k4 += 4) {
            float4 xr[4];
#pragma unroll
            for (int i = 0; i < 4; ++i) xr[i] = *(const float4*)&sX[ty4 + i][k4];
#pragma unroll
            for (int kk = 0; kk < 4; ++kk) {
                float4 w0 = *(const float4*)&sW[k4 + kk][tx4];
                float4 w1 = *(const float4*)&sW[k4 + kk][tx4 + 64];
#pragma unroll
                for (int i = 0; i < 4; ++i) {
                    float xv = ((const float*)&xr[i])[kk];
                    acc0[i][0] += xv * w0.x; acc0[i][1] += xv * w0.y;
                    acc0[i][2] += xv * w0.z; acc0[i][3] += xv * w0.w;
                    acc1[i][0] += xv * w1.x; acc1[i][1] += xv * w1.y;
                    acc1[i][2] += xv * w1.z; acc1[i][3] += xv * w1.w;
                }
            }
        }
    }

    // attention vectors for this thread's 8 columns
    float av0[4], av1[4], dv0[4], dv1[4];
#pragma unroll
    for (int j = 0; j < 4; ++j) {
        av0[j] = asrc[tx4 + j];      av1[j] = asrc[64 + tx4 + j];
        dv0[j] = adst[tx4 + j];      dv1[j] = adst[64 + tx4 + j];
    }

#pragma unroll
    for (int i = 0; i < 4; ++i) {
        int gr = row0 + ty4 + i;
        bool ok = gr < n;
        if (ok) {
            float4* p0 = (float4*)(O + (size_t)gr * 128 + tx4);
            float4* p1 = (float4*)(O + (size_t)gr * 128 + 64 + tx4);
            *p0 = make_float4(acc0[i][0], acc0[i][1], acc0[i][2], acc0[i][3]);
            *p1 = make_float4(acc1[i][0], acc1[i][1], acc1[i][2], acc1[i][3]);
        }
        float ps0 = 0.f, pd0 = 0.f, ps1 = 0.f, pd1 = 0.f;
#pragma unroll
        for (int j = 0; j < 4; ++j) {
            ps0 += acc0[i][j] * av0[j]; pd0 += acc0[i][j] * dv0[j];
            ps1 += acc1[i][j] * av1[j]; pd1 += acc1[i][j] * dv1[j];
        }
        if (H == 8) {
            // head of cols tx*4..: tx>>2 ; head of cols 64+tx*4..: 4+(tx>>2)
#pragma unroll
            for (int off = 1; off < 4; off <<= 1) {
                ps0 += __shfl_xor(ps0, off, 64); pd0 += __shfl_xor(pd0, off, 64);
                ps1 += __shfl_xor(ps1, off, 64); pd1 += __shfl_xor(pd1, off, 64);
            }
            if (ok && (tx & 3) == 0) {
                int h0 = tx >> 2;
                as_out[(size_t)gr * 8 + h0] = ps0;     ad_out[(size_t)gr * 8 + h0] = pd0;
                as_out[(size_t)gr * 8 + 4 + h0] = ps1; ad_out[(size_t)gr * 8 + 4 + h0] = pd1;
            }
        } else {
            float ps = ps0 + ps1, pd = pd0 + pd1;
#pragma unroll
            for (int off = 1; off < 16; off <<= 1) {
                ps += __shfl_xor(ps, off, 64); pd += __shfl_xor(pd, off, 64);
            }
            if (ok && tx == 0) { as_out[gr] = ps; ad_out[gr] = pd; }
        }
    }
}

// ---------------- single-pass aggregation (max-free softmax) ----------------

template <int H>
__global__ __launch_bounds__(256) void agg_kernel(const int* __restrict__ rowptr,
                                                  const int* __restrict__ colsrc,
                                                  const float* __restrict__ hbuf,
                                                  const float* __restrict__ as,
                                                  const float* __restrict__ ad,
                                                  const float* __restrict__ bias,
                                                  float* __restrict__ out, int n, int applyElu) {
    int node = blockIdx.x * 4 + (threadIdx.x >> 6);
    int lane = threadIdx.x & 63;
    if (node >= n) return;
    int beg = rowptr[node];
    int end = rowptr[node + 1];

    int slot = lane >> 4;
    int cl = lane & 15;
    int head = (H == 8) ? (cl >> 1) : 0;
    float adh = ad[(size_t)node * H + head];

    float4 acc0 = make_float4(0.f, 0.f, 0.f, 0.f);
    float4 acc1 = make_float4(0.f, 0.f, 0.f, 0.f);
    float den = 0.f;

#pragma unroll 2
    for (int i = beg + slot; i < end; i += 4) {
        int s = colsrc[i];
        float ev = as[(size_t)s * H + head] + adh;
        ev = (ev > 0.f) ? ev : NEG_SLOPE * ev;
        float w = __expf(ev);
        den += w;
        const float4* hp = (const float4*)(hbuf + (size_t)s * 128 + cl * 8);
        float4 h0 = hp[0];
        float4 h1 = hp[1];
        acc0.x += w * h0.x; acc0.y += w * h0.y; acc0.z += w * h0.z; acc0.w += w * h0.w;
        acc1.x += w * h1.x; acc1.y += w * h1.y; acc1.z += w * h1.z; acc1.w += w * h1.w;
    }

#pragma unroll
    for (int off = 16; off <= 32; off <<= 1) {
        acc0.x += __shfl_xor(acc0.x, off, 64); acc0.y += __shfl_xor(acc0.y, off, 64);
        acc0.z += __shfl_xor(acc0.z, off, 64); acc0.w += __shfl_xor(acc0.w, off, 64);
        acc1.x += __shfl_xor(acc1.x, off, 64); acc1.y += __shfl_xor(acc1.y, off, 64);
        acc1.z += __shfl_xor(acc1.z, off, 64); acc1.w += __shfl_xor(acc1.w, off, 64);
        den += __shfl_xor(den, off, 64);
    }

    if (slot == 0) {
        float inv = 1.0f / den;
        float4 bb0 = ((const float4*)bias)[cl * 2];
        float4 bb1 = ((const float4*)bias)[cl * 2 + 1];
        float4 r0, r1;
        r0.x = acc0.x * inv + bb0.x; r0.y = acc0.y * inv + bb0.y;
        r0.z = acc0.z * inv + bb0.z; r0.w = acc0.w * inv + bb0.w;
        r1.x = acc1.x * inv + bb1.x; r1.y = acc1.y * inv + bb1.y;
        r1.z = acc1.z * inv + bb1.z; r1.w = acc1.w * inv + bb1.w;
        if (applyElu) {
            r0.x = (r0.x > 0.f) ? r0.x : expm1f(r0.x);
            r0.y = (r0.y > 0.f) ? r0.y : expm1f(r0.y);
            r0.z = (r0.z > 0.f) ? r0.z : expm1f(r0.z);
            r0.w = (r0.w > 0.f) ? r0.w : expm1f(r0.w);
            r1.x = (r1.x > 0.f) ? r1.x : expm1f(r1.x);
            r1.y = (r1.y > 0.f) ? r1.y : expm1f(r1.y);
            r1.z = (r1.z > 0.f) ? r1.z : expm1f(r1.z);
            r1.w = (r1.w > 0.f) ? r1.w : expm1f(r1.w);
        }
        float4* p = (float4*)(out + (size_t)node * 128 + cl * 8);
        p[0] = r0; p[1] = r1;
    }
}

// ---------------- launch ----------------

extern "C" void kernel_launch(void* const* d_in, const int* in_sizes, int n_in,
                              void* d_out, int out_size, void* d_ws, size_t ws_size,
                              hipStream_t stream) {
    const float* x    = (const float*)d_in[0];
    const int*   ei   = (const int*)d_in[1];
    const float* W1   = (const float*)d_in[2];
    const float* a_s1 = (const float*)d_in[3];
    const float* a_d1 = (const float*)d_in[4];
    const float* b1   = (const float*)d_in[5];
    const float* W2   = (const float*)d_in[6];
    const float* a_s2 = (const float*)d_in[7];
    const float* a_d2 = (const float*)d_in[8];
    const float* b2   = (const float*)d_in[9];

    const int n  = in_sizes[0] / 128;
    const int e  = in_sizes[1] / 2;
    const int en = e + n;

    char* ws = (char*)d_ws;
    size_t off = 0;
    auto alloc = [&](size_t bytes) -> void* {
        void* p = ws + off;
        off += (bytes + 255) & ~(size_t)255;
        return p;
    };
    float* h1     = (float*)alloc((size_t)n * 128 * 4);
    float* hmid   = (float*)alloc((size_t)n * 128 * 4);
    float* as1    = (float*)alloc((size_t)n * 8 * 4);
    float* ad1    = (float*)alloc((size_t)n * 8 * 4);
    float* as2    = (float*)alloc((size_t)n * 4);
    float* ad2    = (float*)alloc((size_t)n * 4);
    int*   cnt    = (int*)alloc((size_t)n * 4 * 2);
    int*   fillc  = cnt + n;
    int*   rowptr = (int*)alloc((size_t)(n + 1) * 4);
    int*   colsrc = (int*)alloc((size_t)en * 4);

    hipMemsetAsync(cnt, 0, (size_t)n * 8, stream);
    count_kernel<<<(en + 255) / 256, 256, 0, stream>>>(ei, e, n, cnt);
    scan_kernel<<<1, 1024, 0, stream>>>(cnt, rowptr, n);
    fill_kernel<<<(en + 255) / 256, 256, 0, stream>>>(ei, e, n, rowptr, fillc, colsrc);

    int gemm_grid = (n + 63) / 64;
    int node_grid = (n + 3) / 4;

    // layer 1
    gemm_alpha_kernel<8><<<gemm_grid, 256, 0, stream>>>(x, W1, a_s1, a_d1, h1, as1, ad1, n);
    agg_kernel<8><<<node_grid, 256, 0, stream>>>(rowptr, colsrc, h1, as1, ad1, b1, hmid, n, 1);

    // layer 2
    gemm_alpha_kernel<1><<<gemm_grid, 256, 0, stream>>>(hmid, W2, a_s2, a_d2, h1, as2, ad2, n);
    agg_kernel<1><<<node_grid, 256, 0, stream>>>(rowptr, colsrc, h1, as2, ad2, b2, (float*)d_out, n, 0);

    (void)n_in; (void)out_size; (void)ws_size;
}

// Round 4
// 252.274 us; speedup vs baseline: 1.7857x; 1.0698x over previous
//
#include <hip/hip_runtime.h>
#include <hip/hip_bf16.h>

#define NEG_SLOPE 0.2f

__device__ __forceinline__ unsigned short f2bf(float f) {
    unsigned int u = __float_as_uint(f);
    u += 0x7FFFu + ((u >> 16) & 1u);   // RNE
    return (unsigned short)(u >> 16);
}

// ---------------- CSR build ----------------

__global__ void count_kernel(const int* __restrict__ ei, int e, int n, int* __restrict__ cnt) {
    int i = blockIdx.x * blockDim.x + threadIdx.x;
    int total = e + n;
    if (i >= total) return;
    int dst = (i < e) ? ei[e + i] : (i - e);
    atomicAdd(&cnt[dst], 1);
}

__global__ __launch_bounds__(1024) void scan_kernel(const int* __restrict__ cnt, int* __restrict__ rowptr, int n) {
    __shared__ int wsum[16];
    __shared__ int wbase[16];
    int tid = threadIdx.x;
    int wid = tid >> 6, lane = tid & 63;
    int per_wave = ((n + 1023) / 1024) * 64;
    int beg = wid * per_wave;
    int end = min(beg + per_wave, n);
    int s = 0;
    for (int i = beg + lane; i < end; i += 64) s += cnt[i];
#pragma unroll
    for (int off = 32; off; off >>= 1) s += __shfl_xor(s, off, 64);
    if (lane == 0) wsum[wid] = s;
    __syncthreads();
    if (tid == 0) {
        int run = 0;
        for (int w = 0; w < 16; ++w) { wbase[w] = run; run += wsum[w]; }
        rowptr[n] = run;
    }
    __syncthreads();
    int base = wbase[wid];
    for (int i0 = beg; i0 < end; i0 += 64) {
        int i = i0 + lane;
        int v = (i < end) ? cnt[i] : 0;
        int incl = v;
#pragma unroll
        for (int off = 1; off < 64; off <<= 1) {
            int t = __shfl_up(incl, off, 64);
            if (lane >= off) incl += t;
        }
        if (i < end) rowptr[i] = base + incl - v;
        base += __shfl(incl, 63, 64);
    }
}

__global__ void fill_kernel(const int* __restrict__ ei, int e, int n,
                            const int* __restrict__ rowptr, int* __restrict__ fillc,
                            int* __restrict__ colsrc) {
    int i = blockIdx.x * blockDim.x + threadIdx.x;
    int total = e + n;
    if (i >= total) return;
    int src, dst;
    if (i < e) { src = ei[i]; dst = ei[e + i]; }
    else       { src = i - e; dst = i - e; }
    int pos = atomicAdd(&fillc[dst], 1);
    colsrc[rowptr[dst] + pos] = src;
}

// ---------------- GEMM + fused alpha; bf16 h output ----------------
// BM=64, BN=128, BK=32, 256 threads. tx=tid&15 (cols tx*4, 64+tx*4), ty=tid>>4 (rows ty*4..+3)

template <int H>
__global__ __launch_bounds__(256) void gemm_alpha_kernel(const float* __restrict__ X,
                                                         const float* __restrict__ W,
                                                         const float* __restrict__ asrc,
                                                         const float* __restrict__ adst,
                                                         unsigned short* __restrict__ Ob,
                                                         float* __restrict__ as_out,
                                                         float* __restrict__ ad_out, int n) {
    __shared__ float sW[32][128];
    __shared__ float sX[64][36];
    int tid = threadIdx.x;
    int row0 = blockIdx.x * 64;
    int tx = tid & 15, ty = tid >> 4;
    int tx4 = tx * 4, ty4 = ty * 4;

    int xr0 = tid >> 3;
    int xc0 = (tid & 7) * 4;

    float4 xp[2];
    float4 wp[4];

    auto load_chunk = [&](int kc) {
        int k0 = kc * 32;
#pragma unroll
        for (int t = 0; t < 2; ++t) {
            int r = xr0 + t * 32;
            int gr = row0 + r;
            xp[t] = make_float4(0.f, 0.f, 0.f, 0.f);
            if (gr < n) xp[t] = *(const float4*)(X + (size_t)gr * 128 + k0 + xc0);
        }
#pragma unroll
        for (int t = 0; t < 4; ++t) {
            int f = tid + t * 256;
            int kr = f >> 5, c4 = (f & 31) * 4;
            wp[t] = *(const float4*)(W + (size_t)(k0 + kr) * 128 + c4);
        }
    };

    float acc0[4][4], acc1[4][4];
#pragma unroll
    for (int i = 0; i < 4; ++i)
#pragma unroll
        for (int j = 0; j < 4; ++j) { acc0[i][j] = 0.f; acc1[i][j] = 0.f; }

    load_chunk(0);

    for (int kc = 0; kc < 4; ++kc) {
        __syncthreads();
#pragma unroll
        for (int t = 0; t < 2; ++t) {
            int r = xr0 + t * 32;
            *(float4*)&sX[r][xc0] = xp[t];
        }
#pragma unroll
        for (int t = 0; t < 4; ++t) {
            int f = tid + t * 256;
            int kr = f >> 5, c4 = (f & 31) * 4;
            *(float4*)&sW[kr][c4] = wp[t];
        }
        __syncthreads();
        if (kc < 3) load_chunk(kc + 1);

#pragma unroll
        for (int k4 = 0; k4 < 32; k4 += 4) {
            float4 xr[4];
#pragma unroll
            for (int i = 0; i < 4; ++i) xr[i] = *(const float4*)&sX[ty4 + i][k4];
#pragma unroll
            for (int kk = 0; kk < 4; ++kk) {
                float4 w0 = *(const float4*)&sW[k4 + kk][tx4];
                float4 w1 = *(const float4*)&sW[k4 + kk][tx4 + 64];
#pragma unroll
                for (int i = 0; i < 4; ++i) {
                    float xv = ((const float*)&xr[i])[kk];
                    acc0[i][0] += xv * w0.x; acc0[i][1] += xv * w0.y;
                    acc0[i][2] += xv * w0.z; acc0[i][3] += xv * w0.w;
                    acc1[i][0] += xv * w1.x; acc1[i][1] += xv * w1.y;
                    acc1[i][2] += xv * w1.z; acc1[i][3] += xv * w1.w;
                }
            }
        }
    }

    float av0[4], av1[4], dv0[4], dv1[4];
#pragma unroll
    for (int j = 0; j < 4; ++j) {
        av0[j] = asrc[tx4 + j];      av1[j] = asrc[64 + tx4 + j];
        dv0[j] = adst[tx4 + j];      dv1[j] = adst[64 + tx4 + j];
    }

#pragma unroll
    for (int i = 0; i < 4; ++i) {
        int gr = row0 + ty4 + i;
        bool ok = gr < n;
        if (ok) {
            ushort4 o0, o1;
            o0.x = f2bf(acc0[i][0]); o0.y = f2bf(acc0[i][1]);
            o0.z = f2bf(acc0[i][2]); o0.w = f2bf(acc0[i][3]);
            o1.x = f2bf(acc1[i][0]); o1.y = f2bf(acc1[i][1]);
            o1.z = f2bf(acc1[i][2]); o1.w = f2bf(acc1[i][3]);
            *(ushort4*)(Ob + (size_t)gr * 128 + tx4) = o0;
            *(ushort4*)(Ob + (size_t)gr * 128 + 64 + tx4) = o1;
        }
        float ps0 = 0.f, pd0 = 0.f, ps1 = 0.f, pd1 = 0.f;
#pragma unroll
        for (int j = 0; j < 4; ++j) {
            ps0 += acc0[i][j] * av0[j]; pd0 += acc0[i][j] * dv0[j];
            ps1 += acc1[i][j] * av1[j]; pd1 += acc1[i][j] * dv1[j];
        }
        if (H == 8) {
#pragma unroll
            for (int off = 1; off < 4; off <<= 1) {
                ps0 += __shfl_xor(ps0, off, 64); pd0 += __shfl_xor(pd0, off, 64);
                ps1 += __shfl_xor(ps1, off, 64); pd1 += __shfl_xor(pd1, off, 64);
            }
            if (ok && (tx & 3) == 0) {
                int h0 = tx >> 2;
                as_out[(size_t)gr * 8 + h0] = ps0;     ad_out[(size_t)gr * 8 + h0] = pd0;
                as_out[(size_t)gr * 8 + 4 + h0] = ps1; ad_out[(size_t)gr * 8 + 4 + h0] = pd1;
            }
        } else {
            float ps = ps0 + ps1, pd = pd0 + pd1;
#pragma unroll
            for (int off = 1; off < 16; off <<= 1) {
                ps += __shfl_xor(ps, off, 64); pd += __shfl_xor(pd, off, 64);
            }
            if (ok && tx == 0) { as_out[gr] = ps; ad_out[gr] = pd; }
        }
    }
}

// ---------------- single-pass aggregation, bf16 h gather ----------------
// wave per node; slot = lane>>3 (8 edges in flight), cl = lane&7 (16 channels = 32 B)
// H=8: lane cl owns exactly head cl.

template <int H>
__global__ __launch_bounds__(256) void agg_kernel(const int* __restrict__ rowptr,
                                                  const int* __restrict__ colsrc,
                                                  const unsigned short* __restrict__ hb,
                                                  const float* __restrict__ as,
                                                  const float* __restrict__ ad,
                                                  const float* __restrict__ bias,
                                                  float* __restrict__ out, int n, int applyElu) {
    int node = blockIdx.x * 4 + (threadIdx.x >> 6);
    int lane = threadIdx.x & 63;
    if (node >= n) return;
    int beg = rowptr[node];
    int end = rowptr[node + 1];

    int slot = lane >> 3;
    int cl = lane & 7;
    int head = (H == 8) ? cl : 0;
    float adh = ad[(size_t)node * H + head];

    float acc[16];
#pragma unroll
    for (int c = 0; c < 16; ++c) acc[c] = 0.f;
    float den = 0.f;

    for (int i = beg + slot; i < end; i += 8) {
        int s = colsrc[i];
        float ev = as[(size_t)s * H + head] + adh;
        ev = (ev > 0.f) ? ev : NEG_SLOPE * ev;
        float w = __expf(ev);
        den += w;
        const uint4* hp = (const uint4*)(hb + (size_t)s * 128 + cl * 16);
        uint4 a = hp[0];
        uint4 b = hp[1];
        unsigned int u[8] = {a.x, a.y, a.z, a.w, b.x, b.y, b.z, b.w};
#pragma unroll
        for (int k = 0; k < 8; ++k) {
            float lo = __uint_as_float(u[k] << 16);
            float hi = __uint_as_float(u[k] & 0xffff0000u);
            acc[2 * k]     += w * lo;
            acc[2 * k + 1] += w * hi;
        }
    }

    // reduce across the 8 slots (lane strides 8,16,32)
#pragma unroll
    for (int off = 8; off <= 32; off <<= 1) {
        den += __shfl_xor(den, off, 64);
#pragma unroll
        for (int c = 0; c < 16; ++c) acc[c] += __shfl_xor(acc[c], off, 64);
    }

    if (slot == 0) {
        float inv = 1.0f / den;
        float4 r[4];
#pragma unroll
        for (int q = 0; q < 4; ++q) {
            float4 bb = ((const float4*)bias)[cl * 4 + q];
            r[q].x = acc[4 * q]     * inv + bb.x;
            r[q].y = acc[4 * q + 1] * inv + bb.y;
            r[q].z = acc[4 * q + 2] * inv + bb.z;
            r[q].w = acc[4 * q + 3] * inv + bb.w;
            if (applyElu) {
                r[q].x = (r[q].x > 0.f) ? r[q].x : expm1f(r[q].x);
                r[q].y = (r[q].y > 0.f) ? r[q].y : expm1f(r[q].y);
                r[q].z = (r[q].z > 0.f) ? r[q].z : expm1f(r[q].z);
                r[q].w = (r[q].w > 0.f) ? r[q].w : expm1f(r[q].w);
            }
            ((float4*)(out + (size_t)node * 128 + cl * 16))[q] = r[q];
        }
    }
}

// ---------------- launch ----------------

extern "C" void kernel_launch(void* const* d_in, const int* in_sizes, int n_in,
                              void* d_out, int out_size, void* d_ws, size_t ws_size,
                              hipStream_t stream) {
    const float* x    = (const float*)d_in[0];
    const int*   ei   = (const int*)d_in[1];
    const float* W1   = (const float*)d_in[2];
    const float* a_s1 = (const float*)d_in[3];
    const float* a_d1 = (const float*)d_in[4];
    const float* b1   = (const float*)d_in[5];
    const float* W2   = (const float*)d_in[6];
    const float* a_s2 = (const float*)d_in[7];
    const float* a_d2 = (const float*)d_in[8];
    const float* b2   = (const float*)d_in[9];

    const int n  = in_sizes[0] / 128;
    const int e  = in_sizes[1] / 2;
    const int en = e + n;

    char* ws = (char*)d_ws;
    size_t off = 0;
    auto alloc = [&](size_t bytes) -> void* {
        void* p = ws + off;
        off += (bytes + 255) & ~(size_t)255;
        return p;
    };
    unsigned short* hb = (unsigned short*)alloc((size_t)n * 128 * 2);  // bf16 h (reused both layers)
    float* hmid   = (float*)alloc((size_t)n * 128 * 4);
    float* as1    = (float*)alloc((size_t)n * 8 * 4);
    float* ad1    = (float*)alloc((size_t)n * 8 * 4);
    float* as2    = (float*)alloc((size_t)n * 4);
    float* ad2    = (float*)alloc((size_t)n * 4);
    int*   cnt    = (int*)alloc((size_t)n * 4 * 2);
    int*   fillc  = cnt + n;
    int*   rowptr = (int*)alloc((size_t)(n + 1) * 4);
    int*   colsrc = (int*)alloc((size_t)en * 4);

    hipMemsetAsync(cnt, 0, (size_t)n * 8, stream);
    count_kernel<<<(en + 255) / 256, 256, 0, stream>>>(ei, e, n, cnt);
    scan_kernel<<<1, 1024, 0, stream>>>(cnt, rowptr, n);
    fill_kernel<<<(en + 255) / 256, 256, 0, stream>>>(ei, e, n, rowptr, fillc, colsrc);

    int gemm_grid = (n + 63) / 64;
    int node_grid = (n + 3) / 4;

    // layer 1
    gemm_alpha_kernel<8><<<gemm_grid, 256, 0, stream>>>(x, W1, a_s1, a_d1, hb, as1, ad1, n);
    agg_kernel<8><<<node_grid, 256, 0, stream>>>(rowptr, colsrc, hb, as1, ad1, b1, hmid, n, 1);

    // layer 2
    gemm_alpha_kernel<1><<<gemm_grid, 256, 0, stream>>>(hmid, W2, a_s2, a_d2, hb, as2, ad2, n);
    agg_kernel<1><<<node_grid, 256, 0, stream>>>(rowptr, colsrc, hb, as2, ad2, b2, (float*)d_out, n, 0);

    (void)n_in; (void)out_size; (void)ws_size;
}

// Round 5
// 215.193 us; speedup vs baseline: 2.0933x; 1.1723x over previous
//
#include <hip/hip_runtime.h>
#include <hip/hip_bf16.h>

#define NEG_SLOPE 0.2f

__device__ __forceinline__ unsigned short f2bf(float f) {
    unsigned int u = __float_as_uint(f);
    u += 0x7FFFu + ((u >> 16) & 1u);   // RNE
    return (unsigned short)(u >> 16);
}

// ---------------- CSR build ----------------

__global__ void count_kernel(const int* __restrict__ ei, int e, int n, int* __restrict__ cnt) {
    int i = blockIdx.x * blockDim.x + threadIdx.x;
    int total = e + n;
    if (i >= total) return;
    int dst = (i < e) ? ei[e + i] : (i - e);
    atomicAdd(&cnt[dst], 1);
}

// block b sums cnt[b*1024 .. b*1024+1023]
__global__ __launch_bounds__(256) void scanA_kernel(const int* __restrict__ cnt, int* __restrict__ bsum, int n) {
    int b = blockIdx.x, t = threadIdx.x;
    int base = b * 1024;
    int s = 0;
#pragma unroll
    for (int q = 0; q < 4; ++q) {
        int i = base + t + q * 256;
        if (i < n) s += cnt[i];
    }
    int lane = t & 63, wid = t >> 6;
#pragma unroll
    for (int off = 32; off; off >>= 1) s += __shfl_xor(s, off, 64);
    __shared__ int ws[4];
    if (lane == 0) ws[wid] = s;
    __syncthreads();
    if (t == 0) bsum[b] = ws[0] + ws[1] + ws[2] + ws[3];
}

// single wave: exclusive scan of nb block sums; writes rowptr[n]=total
__global__ __launch_bounds__(64) void scanB_kernel(const int* __restrict__ bsum, int* __restrict__ bbase,
                                                   int* __restrict__ rowptr, int nb, int n) {
    int t = threadIdx.x;
    int carry = 0;
    for (int c = 0; c < nb; c += 64) {
        int i = c + t;
        int v = (i < nb) ? bsum[i] : 0;
        int incl = v;
#pragma unroll
        for (int off = 1; off < 64; off <<= 1) {
            int u = __shfl_up(incl, off, 64);
            if (t >= off) incl += u;
        }
        if (i < nb) bbase[i] = carry + incl - v;
        carry += __shfl(incl, 63, 64);
    }
    if (t == 0) rowptr[n] = carry;
}

// block b: local exclusive scan of its 1024 cnt values + bbase[b] -> rowptr
__global__ __launch_bounds__(256) void scanC_kernel(const int* __restrict__ cnt, const int* __restrict__ bbase,
                                                    int* __restrict__ rowptr, int n) {
    int b = blockIdx.x, t = threadIdx.x;
    int idx = b * 1024 + t * 4;
    int4 v = make_int4(0, 0, 0, 0);
    if (idx + 3 < n) v = *(const int4*)(cnt + idx);
    else {
        if (idx < n)     v.x = cnt[idx];
        if (idx + 1 < n) v.y = cnt[idx + 1];
        if (idx + 2 < n) v.z = cnt[idx + 2];
        if (idx + 3 < n) v.w = cnt[idx + 3];
    }
    int s0 = v.x, s1 = s0 + v.y, s2 = s1 + v.z, s3 = s2 + v.w;
    int tot = s3;
    int lane = t & 63, wid = t >> 6;
    int incl = tot;
#pragma unroll
    for (int off = 1; off < 64; off <<= 1) {
        int u = __shfl_up(incl, off, 64);
        if (lane >= off) incl += u;
    }
    __shared__ int wtot[4];
    if (lane == 63) wtot[wid] = incl;
    __syncthreads();
    int woff = 0;
    for (int w = 0; w < wid; ++w) woff += wtot[w];
    int ex = incl - tot + woff + bbase[b];
    if (idx < n)     rowptr[idx]     = ex;
    if (idx + 1 < n) rowptr[idx + 1] = ex + s0;
    if (idx + 2 < n) rowptr[idx + 2] = ex + s1;
    if (idx + 3 < n) rowptr[idx + 3] = ex + s2;
}

__global__ void fill_kernel(const int* __restrict__ ei, int e, int n,
                            const int* __restrict__ rowptr, int* __restrict__ fillc,
                            int* __restrict__ colsrc) {
    int i = blockIdx.x * blockDim.x + threadIdx.x;
    int total = e + n;
    if (i >= total) return;
    int src, dst;
    if (i < e) { src = ei[i]; dst = ei[e + i]; }
    else       { src = i - e; dst = i - e; }
    int pos = atomicAdd(&fillc[dst], 1);
    colsrc[rowptr[dst] + pos] = src;
}

// ---------------- GEMM + fused alpha; bf16 h output ----------------

template <int H>
__global__ __launch_bounds__(256) void gemm_alpha_kernel(const float* __restrict__ X,
                                                         const float* __restrict__ W,
                                                         const float* __restrict__ asrc,
                                                         const float* __restrict__ adst,
                                                         unsigned short* __restrict__ Ob,
                                                         float* __restrict__ as_out,
                                                         float* __restrict__ ad_out, int n) {
    __shared__ float sW[32][128];
    __shared__ float sX[64][36];
    int tid = threadIdx.x;
    int row0 = blockIdx.x * 64;
    int tx = tid & 15, ty = tid >> 4;
    int tx4 = tx * 4, ty4 = ty * 4;

    int xr0 = tid >> 3;
    int xc0 = (tid & 7) * 4;

    float4 xp[2];
    float4 wp[4];

    auto load_chunk = [&](int kc) {
        int k0 = kc * 32;
#pragma unroll
        for (int t = 0; t < 2; ++t) {
            int r = xr0 + t * 32;
            int gr = row0 + r;
            xp[t] = make_float4(0.f, 0.f, 0.f, 0.f);
            if (gr < n) xp[t] = *(const float4*)(X + (size_t)gr * 128 + k0 + xc0);
        }
#pragma unroll
        for (int t = 0; t < 4; ++t) {
            int f = tid + t * 256;
            int kr = f >> 5, c4 = (f & 31) * 4;
            wp[t] = *(const float4*)(W + (size_t)(k0 + kr) * 128 + c4);
        }
    };

    float acc0[4][4], acc1[4][4];
#pragma unroll
    for (int i = 0; i < 4; ++i)
#pragma unroll
        for (int j = 0; j < 4; ++j) { acc0[i][j] = 0.f; acc1[i][j] = 0.f; }

    load_chunk(0);

    for (int kc = 0; kc < 4; ++kc) {
        __syncthreads();
#pragma unroll
        for (int t = 0; t < 2; ++t) {
            int r = xr0 + t * 32;
            *(float4*)&sX[r][xc0] = xp[t];
        }
#pragma unroll
        for (int t = 0; t < 4; ++t) {
            int f = tid + t * 256;
            int kr = f >> 5, c4 = (f & 31) * 4;
            *(float4*)&sW[kr][c4] = wp[t];
        }
        __syncthreads();
        if (kc < 3) load_chunk(kc + 1);

#pragma unroll
        for (int k4 = 0; k4 < 32; k4 += 4) {
            float4 xr[4];
#pragma unroll
            for (int i = 0; i < 4; ++i) xr[i] = *(const float4*)&sX[ty4 + i][k4];
#pragma unroll
            for (int kk = 0; kk < 4; ++kk) {
                float4 w0 = *(const float4*)&sW[k4 + kk][tx4];
                float4 w1 = *(const float4*)&sW[k4 + kk][tx4 + 64];
#pragma unroll
                for (int i = 0; i < 4; ++i) {
                    float xv = ((const float*)&xr[i])[kk];
                    acc0[i][0] += xv * w0.x; acc0[i][1] += xv * w0.y;
                    acc0[i][2] += xv * w0.z; acc0[i][3] += xv * w0.w;
                    acc1[i][0] += xv * w1.x; acc1[i][1] += xv * w1.y;
                    acc1[i][2] += xv * w1.z; acc1[i][3] += xv * w1.w;
                }
            }
        }
    }

    float av0[4], av1[4], dv0[4], dv1[4];
#pragma unroll
    for (int j = 0; j < 4; ++j) {
        av0[j] = asrc[tx4 + j];      av1[j] = asrc[64 + tx4 + j];
        dv0[j] = adst[tx4 + j];      dv1[j] = adst[64 + tx4 + j];
    }

#pragma unroll
    for (int i = 0; i < 4; ++i) {
        int gr = row0 + ty4 + i;
        bool ok = gr < n;
        if (ok) {
            ushort4 o0, o1;
            o0.x = f2bf(acc0[i][0]); o0.y = f2bf(acc0[i][1]);
            o0.z = f2bf(acc0[i][2]); o0.w = f2bf(acc0[i][3]);
            o1.x = f2bf(acc1[i][0]); o1.y = f2bf(acc1[i][1]);
            o1.z = f2bf(acc1[i][2]); o1.w = f2bf(acc1[i][3]);
            *(ushort4*)(Ob + (size_t)gr * 128 + tx4) = o0;
            *(ushort4*)(Ob + (size_t)gr * 128 + 64 + tx4) = o1;
        }
        float ps0 = 0.f, pd0 = 0.f, ps1 = 0.f, pd1 = 0.f;
#pragma unroll
        for (int j = 0; j < 4; ++j) {
            ps0 += acc0[i][j] * av0[j]; pd0 += acc0[i][j] * dv0[j];
            ps1 += acc1[i][j] * av1[j]; pd1 += acc1[i][j] * dv1[j];
        }
        if (H == 8) {
#pragma unroll
            for (int off = 1; off < 4; off <<= 1) {
                ps0 += __shfl_xor(ps0, off, 64); pd0 += __shfl_xor(pd0, off, 64);
                ps1 += __shfl_xor(ps1, off, 64); pd1 += __shfl_xor(pd1, off, 64);
            }
            if (ok && (tx & 3) == 0) {
                int h0 = tx >> 2;
                as_out[(size_t)gr * 8 + h0] = ps0;     ad_out[(size_t)gr * 8 + h0] = pd0;
                as_out[(size_t)gr * 8 + 4 + h0] = ps1; ad_out[(size_t)gr * 8 + 4 + h0] = pd1;
            }
        } else {
            float ps = ps0 + ps1, pd = pd0 + pd1;
#pragma unroll
            for (int off = 1; off < 16; off <<= 1) {
                ps += __shfl_xor(ps, off, 64); pd += __shfl_xor(pd, off, 64);
            }
            if (ok && tx == 0) { as_out[gr] = ps; ad_out[gr] = pd; }
        }
    }
}

// ---------------- single-pass aggregation, bf16 gather ----------------
// wave per node; slot = lane>>4 (4 edges in flight), cl = lane&15 (8 channels = 16 B/lane)
// H=8: head = cl>>1.

template <int H>
__global__ __launch_bounds__(256) void agg_kernel(const int* __restrict__ rowptr,
                                                  const int* __restrict__ colsrc,
                                                  const unsigned short* __restrict__ hb,
                                                  const float* __restrict__ as,
                                                  const float* __restrict__ ad,
                                                  const float* __restrict__ bias,
                                                  float* __restrict__ out, int n, int applyElu) {
    int node = blockIdx.x * 4 + (threadIdx.x >> 6);
    int lane = threadIdx.x & 63;
    if (node >= n) return;
    int beg = rowptr[node];
    int end = rowptr[node + 1];

    int slot = lane >> 4;
    int cl = lane & 15;
    int head = (H == 8) ? (cl >> 1) : 0;
    float adh = ad[(size_t)node * H + head];

    float acc[8];
#pragma unroll
    for (int c = 0; c < 8; ++c) acc[c] = 0.f;
    float den = 0.f;

#pragma unroll 2
    for (int i = beg + slot; i < end; i += 4) {
        int s = colsrc[i];
        float ev = as[(size_t)s * H + head] + adh;
        ev = (ev > 0.f) ? ev : NEG_SLOPE * ev;
        float w = __expf(ev);
        den += w;
        uint4 a = *(const uint4*)(hb + (size_t)s * 128 + cl * 8);
        unsigned int u[4] = {a.x, a.y, a.z, a.w};
#pragma unroll
        for (int k = 0; k < 4; ++k) {
            float lo = __uint_as_float(u[k] << 16);
            float hi = __uint_as_float(u[k] & 0xffff0000u);
            acc[2 * k]     += w * lo;
            acc[2 * k + 1] += w * hi;
        }
    }

    // reduce across 4 slots (strides 16, 32)
#pragma unroll
    for (int off = 16; off <= 32; off <<= 1) {
        den += __shfl_xor(den, off, 64);
#pragma unroll
        for (int c = 0; c < 8; ++c) acc[c] += __shfl_xor(acc[c], off, 64);
    }

    if (slot == 0) {
        float inv = 1.0f / den;
        float4 r[2];
#pragma unroll
        for (int q = 0; q < 2; ++q) {
            float4 bb = ((const float4*)bias)[cl * 2 + q];
            r[q].x = acc[4 * q]     * inv + bb.x;
            r[q].y = acc[4 * q + 1] * inv + bb.y;
            r[q].z = acc[4 * q + 2] * inv + bb.z;
            r[q].w = acc[4 * q + 3] * inv + bb.w;
            if (applyElu) {
                r[q].x = (r[q].x > 0.f) ? r[q].x : expm1f(r[q].x);
                r[q].y = (r[q].y > 0.f) ? r[q].y : expm1f(r[q].y);
                r[q].z = (r[q].z > 0.f) ? r[q].z : expm1f(r[q].z);
                r[q].w = (r[q].w > 0.f) ? r[q].w : expm1f(r[q].w);
            }
            ((float4*)(out + (size_t)node * 128 + cl * 8))[q] = r[q];
        }
    }
}

// ---------------- launch ----------------

extern "C" void kernel_launch(void* const* d_in, const int* in_sizes, int n_in,
                              void* d_out, int out_size, void* d_ws, size_t ws_size,
                              hipStream_t stream) {
    const float* x    = (const float*)d_in[0];
    const int*   ei   = (const int*)d_in[1];
    const float* W1   = (const float*)d_in[2];
    const float* a_s1 = (const float*)d_in[3];
    const float* a_d1 = (const float*)d_in[4];
    const float* b1   = (const float*)d_in[5];
    const float* W2   = (const float*)d_in[6];
    const float* a_s2 = (const float*)d_in[7];
    const float* a_d2 = (const float*)d_in[8];
    const float* b2   = (const float*)d_in[9];

    const int n  = in_sizes[0] / 128;
    const int e  = in_sizes[1] / 2;
    const int en = e + n;
    const int nb = (n + 1023) / 1024;

    char* ws = (char*)d_ws;
    size_t off = 0;
    auto alloc = [&](size_t bytes) -> void* {
        void* p = ws + off;
        off += (bytes + 255) & ~(size_t)255;
        return p;
    };
    unsigned short* hb = (unsigned short*)alloc((size_t)n * 128 * 2);
    float* hmid   = (float*)alloc((size_t)n * 128 * 4);
    float* as1    = (float*)alloc((size_t)n * 8 * 4);
    float* ad1    = (float*)alloc((size_t)n * 8 * 4);
    float* as2    = (float*)alloc((size_t)n * 4);
    float* ad2    = (float*)alloc((size_t)n * 4);
    int*   cnt    = (int*)alloc((size_t)n * 4 * 2);
    int*   fillc  = cnt + n;
    int*   rowptr = (int*)alloc((size_t)(n + 1) * 4);
    int*   colsrc = (int*)alloc((size_t)en * 4);
    int*   bsum   = (int*)alloc((size_t)nb * 4);
    int*   bbase  = (int*)alloc((size_t)nb * 4);

    hipMemsetAsync(cnt, 0, (size_t)n * 8, stream);
    count_kernel<<<(en + 255) / 256, 256, 0, stream>>>(ei, e, n, cnt);
    scanA_kernel<<<nb, 256, 0, stream>>>(cnt, bsum, n);
    scanB_kernel<<<1, 64, 0, stream>>>(bsum, bbase, rowptr, nb, n);
    scanC_kernel<<<nb, 256, 0, stream>>>(cnt, bbase, rowptr, n);
    fill_kernel<<<(en + 255) / 256, 256, 0, stream>>>(ei, e, n, rowptr, fillc, colsrc);

    int gemm_grid = (n + 63) / 64;
    int node_grid = (n + 3) / 4;

    // layer 1
    gemm_alpha_kernel<8><<<gemm_grid, 256, 0, stream>>>(x, W1, a_s1, a_d1, hb, as1, ad1, n);
    agg_kernel<8><<<node_grid, 256, 0, stream>>>(rowptr, colsrc, hb, as1, ad1, b1, hmid, n, 1);

    // layer 2
    gemm_alpha_kernel<1><<<gemm_grid, 256, 0, stream>>>(hmid, W2, a_s2, a_d2, hb, as2, ad2, n);
    agg_kernel<1><<<node_grid, 256, 0, stream>>>(rowptr, colsrc, hb, as2, ad2, b2, (float*)d_out, n, 0);

    (void)n_in; (void)out_size; (void)ws_size;
}